// Round 2
// baseline (205.268 us; speedup 1.0000x reference)
//
#include <hip/hip_runtime.h>
#include <hip/hip_bf16.h>
#include <math.h>

__device__ __forceinline__ float us2f(unsigned short u) {
    union { unsigned int i; float f; } cv;
    cv.i = ((unsigned int)u) << 16;
    return cv.f;
}

// Runtime-dtype load: inputs may be f32 (as reference declares) or bf16
// (dataset-converted). bf flag decided at runtime from an all-ones tensor.
__device__ __forceinline__ float ldv(const void* p, int i, int bf) {
    return bf ? us2f(((const unsigned short*)p)[i]) : ((const float*)p)[i];
}

__device__ __forceinline__ int detect_bf(const void* ones_vec) {
    // f32 1.0 -> 0x3F800000 ; bf16 [1.0,1.0] -> 0x3F803F80
    return ((const unsigned int*)ones_vec)[0] == 0x3F803F80u;
}

__device__ __forceinline__ float wave_sum64(float v) {
#pragma unroll
    for (int m = 32; m > 0; m >>= 1) v += __shfl_xor(v, m, 64);
    return v;
}

__device__ __forceinline__ float gelu_exact(float x) {
    return 0.5f * x * (1.0f + erff(x * 0.7071067811865475f));
}

// ---------------------------------------------------------------------------
// Stage 1 (two independent jobs in one launch):
//  blocks 0..15  : tokenizer for batch b -> H[b][j][d], j=0..6 (CLS + pooled 0..5)
//  blocks 16..52 : M2[(j*64+d)*256+o] = sum_c comp_w[o,c,d]*dconv_w[c,j+6]
//                  BE[o] = comp_b[o] + sum_{c,d} comp_w[o,c,d]*dconv_b[c]
// Only token n=0 (CLS) survives to the output, and the ds-conv radius is 6,
// so only H rows 0..6 (CLS + pooled tokens 0..5) are ever needed.
// ---------------------------------------------------------------------------
__global__ __launch_bounds__(448) void k_stage1(
    const void* __restrict__ x,        // [16][22][3000]
    const void* __restrict__ conv_w,   // [64][22][13]
    const void* __restrict__ conv_b,   // [64]
    const void* __restrict__ cls,      // [64]
    const void* __restrict__ tok_g, const void* __restrict__ tok_b,  // [64]
    const void* __restrict__ comp_w,   // [256][256][64]
    const void* __restrict__ dconv_w,  // [256][13]
    const void* __restrict__ dconv_b,  // [256]
    const void* __restrict__ comp_b,   // [256]
    float* __restrict__ H,   // [16][7][64]
    float* __restrict__ M2,  // [448][256]  (index (j*64+d)*256+o)
    float* __restrict__ BE)  // [256]
{
    int tid = threadIdx.x;
    int bf = detect_bf(tok_g);
    if (blockIdx.x < 16) {
        // ------------- tokenizer -------------
        __shared__ float sx[22 * 41];          // x[b, :, 0:41]
        __shared__ float schunk[8 * 13 * 64];  // conv_w chunk, [(cc*13+k)][d]
        int b = blockIdx.x;
        for (int i = tid; i < 22 * 41; i += 448) {
            int c = i / 41, p = i - c * 41;
            sx[i] = ldv(x, (b * 22 + c) * 3000 + p, bf);
        }
        int w = tid >> 6, lane = tid & 63;   // lane = output channel d
        int t = w - 1;                       // pooled token (w>=1), conv pos p=3t..3t+2
        float cb = ldv(conv_b, lane, bf);
        float a0 = cb, a1 = cb, a2 = cb;
        for (int c0 = 0; c0 < 22; c0 += 8) {
            int csz = (22 - c0 < 8) ? (22 - c0) : 8;
            int n = csz * 13 * 64;
            __syncthreads();   // sx ready (1st iter) / schunk reads done (later)
            for (int i = tid; i < n; i += 448) {
                int d = i / (csz * 13), r = i - d * (csz * 13);
                schunk[r * 64 + d] = ldv(conv_w, d * 286 + c0 * 13 + r, bf);
            }
            __syncthreads();
            if (w >= 1) {
                for (int cc = 0; cc < csz; ++cc) {
                    const float* xr = &sx[(c0 + cc) * 41];
#pragma unroll
                    for (int k = 0; k < 13; ++k) {
                        float wv = schunk[(cc * 13 + k) * 64 + lane];
                        int i0 = 6 * t - 6 + k;   // x idx for p=3t (pad 6, stride 2)
                        if (i0 >= 0)     a0 += xr[i0] * wv;
                        if (i0 + 2 >= 0) a1 += xr[i0 + 2] * wv;
                        if (i0 + 4 >= 0) a2 += xr[i0 + 4] * wv;
                    }
                }
            }
        }
        float val;
        if (w == 0) {
            val = ldv(cls, lane, bf);        // CLS token (row 0)
        } else {
            // gelu BEFORE maxpool (gelu is non-monotonic near 0 is false but
            // reference applies gelu then pools — keep exact order anyway)
            val = fmaxf(fmaxf(gelu_exact(a0), gelu_exact(a1)), gelu_exact(a2));
        }
        // LN over d=64 (one wave), biased variance, eps=1e-5
        float mean = wave_sum64(val) * (1.0f / 64.0f);
        float dv = val - mean;
        float var = wave_sum64(dv * dv) * (1.0f / 64.0f);
        float hn = dv * rsqrtf(var + 1e-5f) * ldv(tok_g, lane, bf) + ldv(tok_b, lane, bf);
        H[b * 448 + w * 64 + lane] = hn;
    } else {
        // ------------- merged-weight precompute -------------
        __shared__ float s_dsw[256 * 7];  // dconv_w[c][k=6..12]
        __shared__ float s_dcb[256];
        for (int i = tid; i < 256 * 7; i += 448) {
            int c = i / 7, j = i - c * 7;
            s_dsw[i] = ldv(dconv_w, c * 13 + 6 + j, bf);
        }
        for (int i = tid; i < 256; i += 448) s_dcb[i] = ldv(dconv_b, i, bf);
        __syncthreads();

        int gid = (blockIdx.x - 16) * 448 + tid;   // waves stay 64-aligned in gid
        if (gid < 16384) {
            int o = gid >> 6, d = gid & 63;        // lane = d within the wave
            float acc0 = 0, acc1 = 0, acc2 = 0, acc3 = 0, acc4 = 0, acc5 = 0, acc6 = 0;
            float ab = 0;
            int base = o * 16384 + d;              // stride 64 over c -> coalesced
#pragma unroll 4
            for (int c = 0; c < 256; ++c) {
                float wv = ldv(comp_w, base + c * 64, bf);
                const float* ds = &s_dsw[c * 7];
                acc0 += wv * ds[0]; acc1 += wv * ds[1]; acc2 += wv * ds[2];
                acc3 += wv * ds[3]; acc4 += wv * ds[4]; acc5 += wv * ds[5];
                acc6 += wv * ds[6];
                ab   += wv * s_dcb[c];
            }
            M2[(0 * 64 + d) * 256 + o] = acc0;
            M2[(1 * 64 + d) * 256 + o] = acc1;
            M2[(2 * 64 + d) * 256 + o] = acc2;
            M2[(3 * 64 + d) * 256 + o] = acc3;
            M2[(4 * 64 + d) * 256 + o] = acc4;
            M2[(5 * 64 + d) * 256 + o] = acc5;
            M2[(6 * 64 + d) * 256 + o] = acc6;
            ab = wave_sum64(ab);                  // reduce over d
            if ((tid & 63) == 0) BE[o] = ldv(comp_b, o, bf) + ab;
        }
    }
}

// ---------------------------------------------------------------------------
// Stage 2: per-batch block. z -> LN -> GELU -> gate -> top2 softmax ->
// experts + universal -> combine -> LN -> out (CLS token only).
// ---------------------------------------------------------------------------
__device__ __forceinline__ float block_sum256(float v, float* sh4) {
    int lane = threadIdx.x & 63, w = threadIdx.x >> 6;
    v = wave_sum64(v);
    __syncthreads();            // protect sh4 from previous use
    if (lane == 0) sh4[w] = v;
    __syncthreads();
    return sh4[0] + sh4[1] + sh4[2] + sh4[3];
}

__global__ __launch_bounds__(256) void k_stage2(
    const float* __restrict__ H, const float* __restrict__ M2, const float* __restrict__ BE,
    const int* __restrict__ task_ids,
    const void* __restrict__ tok_g,     // dtype detector only
    const void* __restrict__ ds_g, const void* __restrict__ ds_b,
    const void* __restrict__ task_embed,            // [4][256]
    const void* __restrict__ gate_w, const void* __restrict__ gate_b,  // [512][8],[8]
    const void* __restrict__ exp_w, const void* __restrict__ exp_b,    // [8][256][256],[8][256]
    const void* __restrict__ uni_w, const void* __restrict__ uni_b,    // [256][256],[256]
    const void* __restrict__ out_g, const void* __restrict__ out_b,    // [256]
    void* __restrict__ out)  // [16][256], dtype matches inputs
{
    __shared__ float sh_h[448];
    __shared__ float sh_tok[256];
    __shared__ float sh_red[4];
    __shared__ float sh_part[256 * 8];
    __shared__ float sh_g[3];
    __shared__ int   sh_e[2];

    int b = blockIdx.x, o = threadIdx.x;
    int bf = detect_bf(tok_g);

    for (int i = o; i < 448; i += 256) sh_h[i] = H[b * 448 + i];
    __syncthreads();

    // z_out[b,o] = BE[o] + sum_{jd} M2[jd][o] * h[jd]   (coalesced over o)
    float acc0 = 0, acc1 = 0, acc2 = 0, acc3 = 0;
    for (int jd = 0; jd < 448; jd += 4) {
        acc0 += M2[(jd + 0) * 256 + o] * sh_h[jd + 0];
        acc1 += M2[(jd + 1) * 256 + o] * sh_h[jd + 1];
        acc2 += M2[(jd + 2) * 256 + o] * sh_h[jd + 2];
        acc3 += M2[(jd + 3) * 256 + o] * sh_h[jd + 3];
    }
    float z = BE[o] + ((acc0 + acc1) + (acc2 + acc3));

    // LN over 256, then GELU -> tokens
    float mean = block_sum256(z, sh_red) * (1.0f / 256.0f);
    float dz = z - mean;
    float var = block_sum256(dz * dz, sh_red) * (1.0f / 256.0f);
    float tok = gelu_exact(dz * rsqrtf(var + 1e-5f) * ldv(ds_g, o, bf) + ldv(ds_b, o, bf));
    sh_tok[o] = tok;

    // gate logits: T_cat = [tokens, task_vec] (512) @ gate_w (512x8) + gate_b
    int task = task_ids[b];
    float tv = ldv(task_embed, task * 256 + o, bf);
#pragma unroll
    for (int e = 0; e < 8; ++e)
        sh_part[o * 8 + e] = tok * ldv(gate_w, o * 8 + e, bf)
                           + tv  * ldv(gate_w, (256 + o) * 8 + e, bf);
    __syncthreads();
    for (int s = 128; s > 0; s >>= 1) {
        if (o < s) {
#pragma unroll
            for (int e = 0; e < 8; ++e) sh_part[o * 8 + e] += sh_part[(o + s) * 8 + e];
        }
        __syncthreads();
    }
    if (o == 0) {
        float lg[8];
#pragma unroll
        for (int e = 0; e < 8; ++e) lg[e] = sh_part[e] + ldv(gate_b, e, bf);
        int e0 = 0;
        for (int e = 1; e < 8; ++e) if (lg[e] > lg[e0]) e0 = e;   // stable: first max
        int e1 = (e0 == 0) ? 1 : 0;
        for (int e = 0; e < 8; ++e) if (e != e0 && lg[e] > lg[e1]) e1 = e;
        // softmax over top-2 (v0 >= v1): g0 >= 0.5, omega = 1 - g0
        float g0 = 1.0f / (1.0f + expf(lg[e1] - lg[e0]));
        sh_g[0] = g0; sh_g[1] = 1.0f - g0; sh_g[2] = 1.0f - g0;
        sh_e[0] = e0; sh_e[1] = e1;
    }
    __syncthreads();
    int e0 = sh_e[0], e1 = sh_e[1];
    float g0 = sh_g[0], g1 = sh_g[1], om = sh_g[2];

    // two experts + universal matvecs (all coalesced over o)
    float a0 = ldv(exp_b, e0 * 256 + o, bf);
    float a1 = ldv(exp_b, e1 * 256 + o, bf);
    float au = ldv(uni_b, o, bf);
    int w0 = e0 * 65536 + o;
    int w1 = e1 * 65536 + o;
#pragma unroll 4
    for (int d = 0; d < 256; ++d) {
        float t = sh_tok[d];
        a0 += t * ldv(exp_w, w0 + d * 256, bf);
        a1 += t * ldv(exp_w, w1 + d * 256, bf);
        au += t * ldv(uni_w, o + d * 256, bf);
    }
    float y = g0 * gelu_exact(a0) + g1 * gelu_exact(a1) + om * gelu_exact(au);

    // final LN
    float m2 = block_sum256(y, sh_red) * (1.0f / 256.0f);
    float dy = y - m2;
    float v2 = block_sum256(dy * dy, sh_red) * (1.0f / 256.0f);
    float res = dy * rsqrtf(v2 + 1e-5f) * ldv(out_g, o, bf) + ldv(out_b, o, bf);

    if (bf) ((__hip_bfloat16*)out)[b * 256 + o] = __float2bfloat16(res);
    else    ((float*)out)[b * 256 + o] = res;
}

// ---------------------------------------------------------------------------
extern "C" void kernel_launch(void* const* d_in, const int* in_sizes, int n_in,
                              void* d_out, int out_size, void* d_ws, size_t ws_size,
                              hipStream_t stream) {
    const void* x         = d_in[0];
    const int* task_ids   = (const int*)d_in[1];
    const void* conv_w    = d_in[2];
    const void* conv_b    = d_in[3];
    const void* cls       = d_in[4];
    const void* tok_g     = d_in[5];
    const void* tok_b     = d_in[6];
    const void* ds_conv_w = d_in[7];
    const void* ds_conv_b = d_in[8];
    const void* ds_comp_w = d_in[9];
    const void* ds_comp_b = d_in[10];
    const void* ds_g      = d_in[11];
    const void* ds_b      = d_in[12];
    const void* task_embed= d_in[13];
    const void* gate_w    = d_in[14];
    const void* gate_b    = d_in[15];
    const void* exp_w     = d_in[16];
    const void* exp_b     = d_in[17];
    const void* uni_w     = d_in[18];
    const void* uni_b     = d_in[19];
    const void* out_g     = d_in[20];
    const void* out_b     = d_in[21];

    float* ws = (float*)d_ws;
    float* H  = ws;                    // 16*7*64        = 7168 floats
    float* M2 = ws + 7168;             // 448*256        = 114688 floats
    float* BE = ws + 7168 + 114688;    // 256 floats     (total ~488 KB)

    hipLaunchKernelGGL(k_stage1, dim3(53), dim3(448), 0, stream,
                       x, conv_w, conv_b, cls, tok_g, tok_b,
                       ds_comp_w, ds_conv_w, ds_conv_b, ds_comp_b,
                       H, M2, BE);
    hipLaunchKernelGGL(k_stage2, dim3(16), dim3(256), 0, stream,
                       H, M2, BE, task_ids, tok_g, ds_g, ds_b, task_embed,
                       gate_w, gate_b, exp_w, exp_b, uni_w, uni_b,
                       out_g, out_b, d_out);
}

// Round 3
// 165.698 us; speedup vs baseline: 1.2388x; 1.2388x over previous
//
#include <hip/hip_runtime.h>
#include <hip/hip_bf16.h>
#include <math.h>

__device__ __forceinline__ float us2f(unsigned short u) {
    union { unsigned int i; float f; } cv;
    cv.i = ((unsigned int)u) << 16;
    return cv.f;
}

// Inputs may be f32 (reference dtype) or bf16 (dataset-converted; confirmed
// bf16 by round-2 absmax). Detected at runtime from tok_g (all-ones):
// f32 1.0 -> 0x3F800000 ; bf16 [1.0,1.0] -> 0x3F803F80.
__device__ __forceinline__ int detect_bf(const void* ones_vec) {
    return ((const unsigned int*)ones_vec)[0] == 0x3F803F80u;
}

template<int BF>
__device__ __forceinline__ float ldg(const void* p, int i) {
    return BF ? us2f(((const unsigned short*)p)[i]) : ((const float*)p)[i];
}

__device__ __forceinline__ float wave_sum64(float v) {
#pragma unroll
    for (int m = 32; m > 0; m >>= 1) v += __shfl_xor(v, m, 64);
    return v;
}

__device__ __forceinline__ float gelu_exact(float x) {
    return 0.5f * x * (1.0f + erff(x * 0.7071067811865475f));
}

// block-wide (1024-thread) sum; all threads must call; sh16 = 16 floats
__device__ __forceinline__ float bsum16(float v, float* sh16) {
    int lane = threadIdx.x & 63, w = threadIdx.x >> 6;
    v = wave_sum64(v);
    __syncthreads();                // protect sh16 from previous use
    if (lane == 0) sh16[w] = v;
    __syncthreads();
    float s = 0;
#pragma unroll
    for (int i = 0; i < 16; ++i) s += sh16[i];
    return s;
}

// ===========================================================================
// Stage 1. grid = 272 x 512 threads.
//  blocks 0..255 : M2 column o=blockIdx: M2[(j*64+d)*256+o] =
//                  sum_c comp_w[o,c,d]*dconv_w[c,j+6]   (8-way c-split)
//                  BE[o] = comp_b[o] + sum_{c,d} comp_w[o,c,d]*dconv_b[c]
//  blocks 256..271: tokenizer for batch b -> H[b][j][d], j=0..6
// Only token n=0 survives to the output; ds-conv radius 6 -> only H rows
// 0..6 (CLS + pooled tokens 0..5) are ever needed.
// ===========================================================================
#define SMEM1_BYTES 41216

template<int BF>
__device__ void stage1_m2(char* smem,
    const void* __restrict__ comp_w, const void* __restrict__ dconv_w,
    const void* __restrict__ dconv_b, const void* __restrict__ comp_b,
    float* __restrict__ M2, float* __restrict__ BE)
{
    int t = threadIdx.x, w = t >> 6, lane = t & 63;   // lane = d, wave = c-chunk
    float* s_dsw = (float*)smem;        // 256*7
    float* s_dcb = s_dsw + 1792;        // 256
    float* sred  = s_dcb + 256;         // 8 waves * 8 slots * 64 d = 4096
    for (int i = t; i < 1792; i += 512) {
        int c = i / 7, j = i - c * 7;
        s_dsw[i] = ldg<BF>(dconv_w, c * 13 + 6 + j);
    }
    for (int i = t; i < 256; i += 512) s_dcb[i] = ldg<BF>(dconv_b, i);
    __syncthreads();

    int o = blockIdx.x;
    float a0 = 0, a1 = 0, a2 = 0, a3 = 0, a4 = 0, a5 = 0, a6 = 0, ab = 0;
    int base = o * 16384 + lane;
    int c0 = w * 32;
#pragma unroll 8
    for (int ci = 0; ci < 32; ++ci) {
        int c = c0 + ci;
        float wv = ldg<BF>(comp_w, base + c * 64);
        const float* ds = &s_dsw[c * 7];
        a0 += wv * ds[0]; a1 += wv * ds[1]; a2 += wv * ds[2]; a3 += wv * ds[3];
        a4 += wv * ds[4]; a5 += wv * ds[5]; a6 += wv * ds[6];
        ab += wv * s_dcb[c];
    }
    sred[(w * 8 + 0) * 64 + lane] = a0;
    sred[(w * 8 + 1) * 64 + lane] = a1;
    sred[(w * 8 + 2) * 64 + lane] = a2;
    sred[(w * 8 + 3) * 64 + lane] = a3;
    sred[(w * 8 + 4) * 64 + lane] = a4;
    sred[(w * 8 + 5) * 64 + lane] = a5;
    sred[(w * 8 + 6) * 64 + lane] = a6;
    sred[(w * 8 + 7) * 64 + lane] = ab;
    __syncthreads();
    if (t < 448) {
        int j = t >> 6, d = t & 63;
        float s = 0;
#pragma unroll
        for (int ww = 0; ww < 8; ++ww) s += sred[(ww * 8 + j) * 64 + d];
        M2[(j * 64 + d) * 256 + o] = s;
    } else {
        float s = 0;                       // wave 7: reduce ab over d
#pragma unroll
        for (int ww = 0; ww < 8; ++ww) s += sred[(ww * 8 + 7) * 64 + lane];
        s = wave_sum64(s);
        if (lane == 0) BE[o] = ldg<BF>(comp_b, o) + s;
    }
}

template<int BF>
__device__ void stage1_tok(char* smem,
    const void* __restrict__ x, const void* __restrict__ conv_w,
    const void* __restrict__ conv_b, const void* __restrict__ cls,
    const void* __restrict__ tok_g, const void* __restrict__ tok_b,
    float* __restrict__ H)
{
    int t = threadIdx.x, b = blockIdx.x - 256;
    float* sx = (float*)smem;                 // 22*41 = 902 floats
    for (int i = t; i < 902; i += 512) {
        int c = i / 41, p = i - c * 41;
        sx[i] = ldg<BF>(x, (b * 22 + c) * 3000 + p);
    }
    int w = t >> 6, lane = t & 63, tt = w - 1;  // wave 0=CLS, 1..6=tokens, 7 idle
    float val = 0.0f;
    if (BF) {
        unsigned short* swt = (unsigned short*)(smem + 3616);  // 286*64 ushort
        const unsigned short* cwu = (const unsigned short*)conv_w;
        for (int i = t; i < 64 * 286; i += 512) {
            int d = i / 286, r = i - d * 286;
            swt[r * 64 + d] = cwu[i];
        }
        __syncthreads();
        if (w == 0) val = ldg<BF>(cls, lane);
        else if (w <= 6) {
            float cb = ldg<BF>(conv_b, lane);
            float p0 = cb, p1 = cb, p2 = cb;
            for (int c = 0; c < 22; ++c) {
                const float* xr = &sx[c * 41];
#pragma unroll
                for (int k = 0; k < 13; ++k) {
                    float wv = us2f(swt[(c * 13 + k) * 64 + lane]);
                    int i0 = 6 * tt - 6 + k;     // conv pos p=3t (pad 6, stride 2)
                    if (i0 >= 0)     p0 += xr[i0] * wv;
                    if (i0 + 2 >= 0) p1 += xr[i0 + 2] * wv;
                    if (i0 + 4 >= 0) p2 += xr[i0 + 4] * wv;
                }
            }
            // reference order: GELU then maxpool(3)
            val = fmaxf(fmaxf(gelu_exact(p0), gelu_exact(p1)), gelu_exact(p2));
        }
    } else {
        float* schunk = (float*)(smem + 3616);   // 8*13*64 floats
        float cb = ldg<BF>(conv_b, lane);
        float p0 = cb, p1 = cb, p2 = cb;
        for (int c0 = 0; c0 < 22; c0 += 8) {
            int csz = (22 - c0 < 8) ? (22 - c0) : 8;
            int n = csz * 13 * 64;
            __syncthreads();
            for (int i = t; i < n; i += 512) {
                int d = i / (csz * 13), r = i - d * (csz * 13);
                schunk[r * 64 + d] = ldg<BF>(conv_w, d * 286 + c0 * 13 + r);
            }
            __syncthreads();
            if (w >= 1 && w <= 6) {
                for (int cc = 0; cc < csz; ++cc) {
                    const float* xr = &sx[(c0 + cc) * 41];
#pragma unroll
                    for (int k = 0; k < 13; ++k) {
                        float wv = schunk[(cc * 13 + k) * 64 + lane];
                        int i0 = 6 * tt - 6 + k;
                        if (i0 >= 0)     p0 += xr[i0] * wv;
                        if (i0 + 2 >= 0) p1 += xr[i0 + 2] * wv;
                        if (i0 + 4 >= 0) p2 += xr[i0 + 4] * wv;
                    }
                }
            }
        }
        val = (w == 0) ? ldg<BF>(cls, lane)
                       : fmaxf(fmaxf(gelu_exact(p0), gelu_exact(p1)), gelu_exact(p2));
    }
    if (w <= 6) {
        // LN over d=64 (one wave), biased variance, eps=1e-5
        float mean = wave_sum64(val) * (1.0f / 64.0f);
        float dv = val - mean;
        float var = wave_sum64(dv * dv) * (1.0f / 64.0f);
        float hn = dv * rsqrtf(var + 1e-5f) * ldg<BF>(tok_g, lane) + ldg<BF>(tok_b, lane);
        H[b * 448 + w * 64 + lane] = hn;
    }
}

__global__ __launch_bounds__(512) void k_stage1(
    const void* __restrict__ x, const void* __restrict__ conv_w,
    const void* __restrict__ conv_b, const void* __restrict__ cls,
    const void* __restrict__ tok_g, const void* __restrict__ tok_b,
    const void* __restrict__ comp_w, const void* __restrict__ dconv_w,
    const void* __restrict__ dconv_b, const void* __restrict__ comp_b,
    float* __restrict__ H, float* __restrict__ M2, float* __restrict__ BE)
{
    __shared__ char smem[SMEM1_BYTES];
    int bf = detect_bf(tok_g);
    if (blockIdx.x < 256) {
        if (bf) stage1_m2<1>(smem, comp_w, dconv_w, dconv_b, comp_b, M2, BE);
        else    stage1_m2<0>(smem, comp_w, dconv_w, dconv_b, comp_b, M2, BE);
    } else {
        if (bf) stage1_tok<1>(smem, x, conv_w, conv_b, cls, tok_g, tok_b, H);
        else    stage1_tok<0>(smem, x, conv_w, conv_b, cls, tok_g, tok_b, H);
    }
}

// ===========================================================================
// Stage 2: per-batch block, 1024 threads (16 waves), 4-way k-splits.
// z -> LN -> GELU -> gate -> top2 softmax -> experts+universal -> LN -> out.
// ===========================================================================
template<int BF>
__device__ void stage2_body(char* smem,
    const float* __restrict__ H, const float* __restrict__ M2,
    const float* __restrict__ BE, const int* __restrict__ task_ids,
    const void* __restrict__ ds_g, const void* __restrict__ ds_b,
    const void* __restrict__ task_embed,
    const void* __restrict__ gate_w, const void* __restrict__ gate_b,
    const void* __restrict__ exp_w, const void* __restrict__ exp_b,
    const void* __restrict__ uni_w, const void* __restrict__ uni_b,
    const void* __restrict__ out_g, const void* __restrict__ out_b,
    void* __restrict__ out)
{
    float* sh_h   = (float*)smem;        // 448
    float* shp0   = sh_h + 448;          // 1024
    float* shp1   = shp0 + 1024;         // 1024
    float* shp2   = shp1 + 1024;         // 1024
    float* sh_tok = shp2 + 1024;         // 256
    float* sh16   = sh_tok + 256;        // 16
    float* sh_g32 = sh16 + 16;           // 32
    float* sh_sc  = sh_g32 + 32;         // 4 (g0,g1,omega)
    int*   sh_e   = (int*)(sh_sc + 4);   // 2

    int t = threadIdx.x, b = blockIdx.x;
    int o = t & 255, q = t >> 8, lane = t & 63, w = t >> 6;

    for (int i = t; i < 448; i += 1024) sh_h[i] = H[b * 448 + i];
    __syncthreads();

    // ---- z partial: jd-split 4 ways (wave reads 256B contiguous of M2) ----
    float p = 0;
    int jd0 = q * 112;
#pragma unroll 8
    for (int j = 0; j < 112; ++j) {
        int jd = jd0 + j;
        p += M2[jd * 256 + o] * sh_h[jd];
    }
    shp0[q * 256 + o] = p;
    __syncthreads();

    float z = 0, dz = 0, tok = 0;
    if (t < 256)
        z = BE[o] + ((shp0[o] + shp0[256 + o]) + (shp0[512 + o] + shp0[768 + o]));
    float mean = bsum16((t < 256) ? z : 0.0f, sh16) * (1.0f / 256.0f);
    dz = z - mean;
    float var = bsum16((t < 256) ? dz * dz : 0.0f, sh16) * (1.0f / 256.0f);
    if (t < 256) {
        tok = gelu_exact(dz * rsqrtf(var + 1e-5f) * ldg<BF>(ds_g, o) + ldg<BF>(ds_b, o));
        sh_tok[o] = tok;
    }
    __syncthreads();

    // ---- gate logits: q handles experts {2q,2q+1}; reduce over o ----
    int task = task_ids[b];
    {
        float tko = sh_tok[o];
        float tvo = ldg<BF>(task_embed, task * 256 + o);
        int ea = q * 2, eb = q * 2 + 1;
        float p0 = tko * ldg<BF>(gate_w, o * 8 + ea) + tvo * ldg<BF>(gate_w, (256 + o) * 8 + ea);
        float p1 = tko * ldg<BF>(gate_w, o * 8 + eb) + tvo * ldg<BF>(gate_w, (256 + o) * 8 + eb);
        p0 = wave_sum64(p0);
        p1 = wave_sum64(p1);
        if (lane == 0) { sh_g32[w * 2] = p0; sh_g32[w * 2 + 1] = p1; }
    }
    __syncthreads();
    if (t == 0) {
        float lg[8];
#pragma unroll
        for (int e = 0; e < 8; ++e) {
            int qq = e >> 1, r = e & 1;
            float s = ldg<BF>(gate_b, e);
#pragma unroll
            for (int i = 0; i < 4; ++i) s += sh_g32[(qq * 4 + i) * 2 + r];
            lg[e] = s;
        }
        int e0 = 0;
        for (int e = 1; e < 8; ++e) if (lg[e] > lg[e0]) e0 = e;   // stable first-max
        int e1 = (e0 == 0) ? 1 : 0;
        for (int e = 0; e < 8; ++e) if (e != e0 && lg[e] > lg[e1]) e1 = e;
        float g0 = 1.0f / (1.0f + expf(lg[e1] - lg[e0]));  // softmax over top-2
        sh_sc[0] = g0; sh_sc[1] = 1.0f - g0; sh_sc[2] = 1.0f - g0;  // omega = 1-max
        sh_e[0] = e0; sh_e[1] = e1;
    }
    __syncthreads();
    int e0 = sh_e[0], e1 = sh_e[1];
    float g0 = sh_sc[0], g1 = sh_sc[1], om = sh_sc[2];

    // ---- expert + universal matvec partials: d-split 4 ways ----
    float a0 = 0, a1 = 0, au = 0;
    int d0 = q * 64;
    int b0 = e0 * 65536 + o, b1 = e1 * 65536 + o;
#pragma unroll 8
    for (int i = 0; i < 64; ++i) {
        int d = d0 + i;
        float tk = sh_tok[d];
        a0 += tk * ldg<BF>(exp_w, b0 + d * 256);
        a1 += tk * ldg<BF>(exp_w, b1 + d * 256);
        au += tk * ldg<BF>(uni_w, o + d * 256);
    }
    shp0[q * 256 + o] = a0;
    shp1[q * 256 + o] = a1;
    shp2[q * 256 + o] = au;
    __syncthreads();

    float y = 0;
    if (t < 256) {
        float s0 = ldg<BF>(exp_b, e0 * 256 + o) + ((shp0[o] + shp0[256 + o]) + (shp0[512 + o] + shp0[768 + o]));
        float s1 = ldg<BF>(exp_b, e1 * 256 + o) + ((shp1[o] + shp1[256 + o]) + (shp1[512 + o] + shp1[768 + o]));
        float su = ldg<BF>(uni_b, o)            + ((shp2[o] + shp2[256 + o]) + (shp2[512 + o] + shp2[768 + o]));
        y = g0 * gelu_exact(s0) + g1 * gelu_exact(s1) + om * gelu_exact(su);
    }
    float m2v = bsum16((t < 256) ? y : 0.0f, sh16) * (1.0f / 256.0f);
    float dy = y - m2v;
    float v2 = bsum16((t < 256) ? dy * dy : 0.0f, sh16) * (1.0f / 256.0f);
    if (t < 256) {
        float res = dy * rsqrtf(v2 + 1e-5f) * ldg<BF>(out_g, o) + ldg<BF>(out_b, o);
        if (BF) ((__hip_bfloat16*)out)[b * 256 + o] = __float2bfloat16(res);
        else    ((float*)out)[b * 256 + o] = res;
    }
}

__global__ __launch_bounds__(1024) void k_stage2(
    const float* __restrict__ H, const float* __restrict__ M2,
    const float* __restrict__ BE, const int* __restrict__ task_ids,
    const void* __restrict__ tok_g,   // dtype detector
    const void* __restrict__ ds_g, const void* __restrict__ ds_b,
    const void* __restrict__ task_embed,
    const void* __restrict__ gate_w, const void* __restrict__ gate_b,
    const void* __restrict__ exp_w, const void* __restrict__ exp_b,
    const void* __restrict__ uni_w, const void* __restrict__ uni_b,
    const void* __restrict__ out_g, const void* __restrict__ out_b,
    void* __restrict__ out)
{
    __shared__ char smem[(448 + 3 * 1024 + 256 + 16 + 32 + 4 + 2) * 4 + 16];
    int bf = detect_bf(tok_g);
    if (bf) stage2_body<1>(smem, H, M2, BE, task_ids, ds_g, ds_b, task_embed,
                           gate_w, gate_b, exp_w, exp_b, uni_w, uni_b,
                           out_g, out_b, out);
    else    stage2_body<0>(smem, H, M2, BE, task_ids, ds_g, ds_b, task_embed,
                           gate_w, gate_b, exp_w, exp_b, uni_w, uni_b,
                           out_g, out_b, out);
}

// ===========================================================================
extern "C" void kernel_launch(void* const* d_in, const int* in_sizes, int n_in,
                              void* d_out, int out_size, void* d_ws, size_t ws_size,
                              hipStream_t stream) {
    const void* x         = d_in[0];
    const int* task_ids   = (const int*)d_in[1];
    const void* conv_w    = d_in[2];
    const void* conv_b    = d_in[3];
    const void* cls       = d_in[4];
    const void* tok_g     = d_in[5];
    const void* tok_b     = d_in[6];
    const void* ds_conv_w = d_in[7];
    const void* ds_conv_b = d_in[8];
    const void* ds_comp_w = d_in[9];
    const void* ds_comp_b = d_in[10];
    const void* ds_g      = d_in[11];
    const void* ds_b      = d_in[12];
    const void* task_embed= d_in[13];
    const void* gate_w    = d_in[14];
    const void* gate_b    = d_in[15];
    const void* exp_w     = d_in[16];
    const void* exp_b     = d_in[17];
    const void* uni_w     = d_in[18];
    const void* uni_b     = d_in[19];
    const void* out_g     = d_in[20];
    const void* out_b     = d_in[21];

    float* ws = (float*)d_ws;
    float* H  = ws;                    // 16*7*64  = 7168 floats
    float* M2 = ws + 7168;             // 448*256  = 114688 floats
    float* BE = ws + 7168 + 114688;    // 256 floats

    hipLaunchKernelGGL(k_stage1, dim3(272), dim3(512), 0, stream,
                       x, conv_w, conv_b, cls, tok_g, tok_b,
                       ds_comp_w, ds_conv_w, ds_conv_b, ds_comp_b,
                       H, M2, BE);
    hipLaunchKernelGGL(k_stage2, dim3(16), dim3(1024), 0, stream,
                       H, M2, BE, task_ids, tok_g, ds_g, ds_b, task_embed,
                       gate_w, gate_b, exp_w, exp_b, uni_w, uni_b,
                       out_g, out_b, d_out);
}